// Round 11
// baseline (521.405 us; speedup 1.0000x reference)
//
#include <hip/hip_runtime.h>
#include <hip/hip_fp16.h>
#include <math.h>

// SmallRIN forward — 4 dispatches.
//  - prepconv: weight transposes + out_w->fp16 (block-range fused)
//  - recur: scalar-u trig-identity chain, LDS-staged (round-9 proven)
//  - layers: xc+theta+update for BOTH layers + A->fp16, row-local, LDS intermediates
//  - logits: fp16 MFMA 128x128 tile, rb-fast for W reuse (round-9 proven)

#define PHIF 1.6180339887498949f

typedef unsigned short u16;
typedef __attribute__((ext_vector_type(8))) _Float16 f16x8;
typedef __attribute__((ext_vector_type(4))) float f32x4;

constexpr int B = 8, S = 128, V = 32000, D = 256, N = 256, L = 2;
constexpr int TWO_D = 512;
constexpr int M = S * B; // 1024 rows, row index tb = t*B + b

// workspace layout (float units)
constexpr size_t OFF_XR   = 0;                                  // [M][D]
constexpr size_t OFF_XI   = OFF_XR   + (size_t)M * D;           // [M][D]
constexpr size_t OFF_XC   = OFF_XI   + (size_t)M * D;           // (unused, kept for layout)
constexpr size_t OFF_CS   = OFF_XC   + (size_t)M * D;           // (unused)
constexpr size_t OFF_SS   = OFF_CS   + (size_t)M * N;           // (unused)
constexpr size_t OFF_RWT  = OFF_SS   + (size_t)M * N;           // [L][D][N] 1/(1+|Wn|) transposed
constexpr size_t OFF_BNT  = OFF_RWT  + (size_t)L * N * D;       // [L][D][N] Bn transposed
constexpr size_t OFF_IPWT = OFF_BNT  + (size_t)L * N * D;       // [L][2D][D] ip_w^T
constexpr size_t OFF_OPRT = OFF_IPWT + (size_t)L * TWO_D * D;   // [L][N][D]  opr^T
constexpr size_t OFF_OPIT = OFF_OPRT + (size_t)L * N * D;       // [L][N][D]  opi^T
constexpr size_t OFF_FLT_END = OFF_OPIT + (size_t)L * N * D;    // 2,097,152 floats = 8 MB

// fp16 buffers (byte offsets into ws)
constexpr size_t A2_BYTE_OFF = OFF_FLT_END * 4;                       // [M][512] f16 = 1 MB
constexpr size_t W2_BYTE_OFF = A2_BYTE_OFF + (size_t)M * 512 * 2;     // [V][512] f16 = 32.8 MB
constexpr size_t WS_NEED     = W2_BYTE_OFF + (size_t)V * 512 * 2;     // ~41.8 MB

__device__ __forceinline__ u16 f2h(float x) {
    return __half_as_ushort(__float2half(x));   // RNE
}

// ---------------------------------------------------------------- prep + conv_w fused
// blocks [0,1024): transposes; blocks [1024,1024+16000): out_w -> fp16
__global__ __launch_bounds__(256) void prepconv_kernel(const float* __restrict__ Wn,
                                                       const float* __restrict__ Bn,
                                                       const float* __restrict__ ip_w,
                                                       const float* __restrict__ opr,
                                                       const float* __restrict__ opi,
                                                       const float* __restrict__ out_w,
                                                       float* __restrict__ ws,
                                                       u16* __restrict__ W2) {
    int blk = blockIdx.x;
    if (blk < 1024) {
        int i = blk * 256 + threadIdx.x;   // 0..262143
        if (i < L * N * D) {
            int l = i >> 16;
            int r = i & 65535;
            int a = r >> 8;          // slow index of the WRITE
            int c = r & 255;         // fast index of the WRITE (coalesced)
            float wv = Wn[(size_t)l * N * D + (size_t)c * D + a];
            ws[OFF_RWT + i] = 1.0f / (1.0f + fabsf(wv));
            ws[OFF_BNT + i] = Bn[(size_t)l * N * D + (size_t)c * D + a];
            ws[OFF_OPRT + i] = opr[(size_t)l * D * N + (size_t)c * N + a];
            ws[OFF_OPIT + i] = opi[(size_t)l * D * N + (size_t)c * N + a];
        }
        // all i < 262144 valid for IPWT
        int l = i >> 17;
        int r = i & 131071;
        int k = r >> 8;
        int d = r & 255;
        ws[OFF_IPWT + i] = ip_w[(size_t)l * D * TWO_D + (size_t)d * TWO_D + k];
    } else {
        int gid = (blk - 1024) * 256 + threadIdx.x;  // V*128 = 4,096,000
        if (gid >= V * 128) return;
        int v  = gid >> 7;
        int kq = (gid & 127) << 2;
        float4 x = *(const float4*)&out_w[(size_t)v * TWO_D + kq];
        ushort4 h = {f2h(x.x), f2h(x.y), f2h(x.z), f2h(x.w)};
        *(ushort4*)&W2[(size_t)v * 512 + kq] = h;
    }
}

// ---------------------------------------------------------------- recurrence
// Identity: h_r' = cos(th_r+th_i), h_i' = sin(th_r+th_i);
//   th_r+th_i = (h_r+h_i)/wl + 2*b + 2*t*phi  -> scalar chain in u = h_r+h_i.
__global__ __launch_bounds__(64) void recur_kernel(const int* __restrict__ ids,
                                                   const float* __restrict__ emb,
                                                   float* __restrict__ ws) {
    __shared__ int   sid[S];
    __shared__ float swv[S][64];
    __shared__ float sbv[S][64];
    int lane = threadIdx.x;          // 0..63
    int blk  = blockIdx.x;           // 0..31
    int b  = blk >> 2;               // 4 blocks per batch row
    int d  = (blk & 3) * 64 + lane;
    sid[lane]      = ids[b * S + lane];
    sid[64 + lane] = ids[b * S + 64 + lane];
    __syncthreads();
    #pragma unroll 16
    for (int t = 0; t < S; ++t) {
        const float* e = emb + (size_t)sid[t] * TWO_D;
        swv[t][lane] = e[d];
        sbv[t][lane] = e[D + d];
    }
    __syncthreads();
    float* XR = ws + OFF_XR;
    float* XI = ws + OFF_XI;
    float u = 0.f;
    #pragma unroll 8
    for (int t = 0; t < S; ++t) {
        float wl = 1.0f + fabsf(swv[t][lane]);
        float c  = 2.0f * sbv[t][lane] + (2.0f * PHIF) * (float)t;
        float psi = __fdividef(u, wl) + c;
        float sn = __sinf(psi);
        float cs = __cosf(psi);
        size_t row = (size_t)(t * B + b) * D + d;
        XR[row] = cs;
        XI[row] = sn;
        u = cs + sn;
    }
}

// ---------------------------------------------------------------- fused resonant layers
// 4 rows per block (256 blocks = 1/CU). Whole chain row-local:
//   xc (thread=d) -> theta (thread=n) -> update (thread=d), x2 layers,
// all intermediates in LDS; final state written back + converted to fp16 A2.
__global__ __launch_bounds__(256) void layers_kernel(const float* __restrict__ ipb,
                                                     float* __restrict__ ws,
                                                     u16* __restrict__ A2,
                                                     int use_a2) {
    __shared__ float xr[4][D];
    __shared__ float xi[4][D];
    __shared__ float xc[4][D];
    __shared__ float cs[4][N];
    __shared__ float ss[4][N];
    int m0 = blockIdx.x * 4;
    int tid = threadIdx.x;

    #pragma unroll
    for (int r = 0; r < 4; ++r) {
        xr[r][tid] = ws[OFF_XR + (size_t)(m0 + r) * D + tid];
        xi[r][tid] = ws[OFF_XI + (size_t)(m0 + r) * D + tid];
    }
    float tp[4];
    #pragma unroll
    for (int r = 0; r < 4; ++r) tp[r] = (float)((m0 + r) >> 3) * PHIF;

    for (int l = 0; l < L; ++l) {
        __syncthreads();
        // ---- xc phase: thread owns d = tid
        const float* WT = ws + OFF_IPWT + (size_t)l * TWO_D * D;
        float bias = ipb[l * D + tid];
        float a[4];
        #pragma unroll
        for (int r = 0; r < 4; ++r) a[r] = bias;
        #pragma unroll 4
        for (int k = 0; k < D; ++k) {
            float wv = WT[k * D + tid];
            #pragma unroll
            for (int r = 0; r < 4; ++r) a[r] = fmaf(xr[r][k], wv, a[r]);
        }
        #pragma unroll 4
        for (int k = 0; k < D; ++k) {
            float wv = WT[(k + D) * D + tid];
            #pragma unroll
            for (int r = 0; r < 4; ++r) a[r] = fmaf(xi[r][k], wv, a[r]);
        }
        #pragma unroll
        for (int r = 0; r < 4; ++r) xc[r][tid] = a[r];
        __syncthreads();

        // ---- theta phase: thread owns n = tid
        const float* RW = ws + OFF_RWT + (size_t)l * D * N;
        const float* BN = ws + OFF_BNT + (size_t)l * D * N;
        float ac[4] = {0.f, 0.f, 0.f, 0.f};
        float as[4] = {0.f, 0.f, 0.f, 0.f};
        #pragma unroll 2
        for (int d = 0; d < D; ++d) {
            float rw = RW[d * N + tid];
            float bn = BN[d * N + tid];
            #pragma unroll
            for (int r = 0; r < 4; ++r) {
                float th = fmaf(xc[r][d], rw, bn) + tp[r];
                ac[r] += __cosf(th);
                as[r] += __sinf(th);
            }
        }
        #pragma unroll
        for (int r = 0; r < 4; ++r) { cs[r][tid] = ac[r]; ss[r][tid] = as[r]; }
        __syncthreads();

        // ---- update phase: thread owns d = tid
        const float* WR = ws + OFF_OPRT + (size_t)l * N * D;
        const float* WI = ws + OFF_OPIT + (size_t)l * N * D;
        float ur[4] = {0.f, 0.f, 0.f, 0.f};
        float ui[4] = {0.f, 0.f, 0.f, 0.f};
        #pragma unroll 4
        for (int n = 0; n < N; ++n) {
            float wr = WR[n * D + tid];
            float wi = WI[n * D + tid];
            #pragma unroll
            for (int r = 0; r < 4; ++r) {
                ur[r] = fmaf(cs[r][n], wr, ur[r]);
                ui[r] = fmaf(ss[r][n], wi, ui[r]);
            }
        }
        #pragma unroll
        for (int r = 0; r < 4; ++r) {
            float vr = ur[r], vi = ui[r];
            float sgr = 1.0f / (1.0f + expf(-vr));
            float sgi = 1.0f / (1.0f + expf(-vi));
            xr[r][tid] += vr * sgr;
            xi[r][tid] += vi * sgi;
        }
    }
    __syncthreads();
    // ---- write back final state (+fp16 A2 for the MFMA logits)
    #pragma unroll
    for (int r = 0; r < 4; ++r) {
        ws[OFF_XR + (size_t)(m0 + r) * D + tid] = xr[r][tid];
        ws[OFF_XI + (size_t)(m0 + r) * D + tid] = xi[r][tid];
    }
    if (use_a2) {
        #pragma unroll
        for (int r = 0; r < 4; ++r) {
            A2[(size_t)(m0 + r) * 512 + tid]       = f2h(xr[r][tid]);
            A2[(size_t)(m0 + r) * 512 + 256 + tid] = f2h(xi[r][tid]);
        }
    }
}

// ---------------------------------------------------------------- logits via fp16 MFMA
// rb is the FAST block index: 8 consecutive blocks share one W 128-row tile.
__global__ __launch_bounds__(256) void logits_mfma_kernel(const u16* __restrict__ A2,
                                                          const u16* __restrict__ W2,
                                                          const float* __restrict__ out_b,
                                                          float* __restrict__ out) {
    __shared__ u16 sA[128 * 32];  // 8 KB, row-major [128][32]
    __shared__ u16 sW[128 * 32];  // 8 KB
    int rb = blockIdx.x & 7;           // 8 row blocks (fast)
    int cb = blockIdx.x >> 3;          // 250 col blocks
    int tid = threadIdx.x;
    int w = tid >> 6, l = tid & 63;
    int wr = w >> 1, wc = w & 1;

    f32x4 acc[4][4];
    #pragma unroll
    for (int i = 0; i < 4; ++i)
        #pragma unroll
        for (int j = 0; j < 4; ++j) acc[i][j] = (f32x4){0.f, 0.f, 0.f, 0.f};

    int srow = l >> 2;          // 0..15
    int sko  = (l & 3) * 8;     // 0,8,16,24 (u16 units -> 16B)
    int kg = (l >> 4) * 8;      // frag k offset
    int rl = l & 15;            // frag row/col

    for (int kk = 0; kk < 512; kk += 32) {
        #pragma unroll
        for (int j = 0; j < 2; ++j) {
            int rloc = (w * 2 + j) * 16 + srow;
            const u16* sa = A2 + (size_t)(rb * 128 + rloc) * 512 + kk + sko;
            const u16* sw = W2 + (size_t)(cb * 128 + rloc) * 512 + kk + sko;
            u16* da = &sA[rloc * 32 + sko];
            u16* dw = &sW[rloc * 32 + sko];
            __builtin_amdgcn_global_load_lds((const __attribute__((address_space(1))) void*)sa,
                                             (__attribute__((address_space(3))) void*)da, 16, 0, 0);
            __builtin_amdgcn_global_load_lds((const __attribute__((address_space(1))) void*)sw,
                                             (__attribute__((address_space(3))) void*)dw, 16, 0, 0);
        }
        __syncthreads();
        f16x8 af[4], wf[4];
        #pragma unroll
        for (int f = 0; f < 4; ++f) {
            af[f] = *(const f16x8*)&sA[(wr * 64 + f * 16 + rl) * 32 + kg];
            wf[f] = *(const f16x8*)&sW[(wc * 64 + f * 16 + rl) * 32 + kg];
        }
        #pragma unroll
        for (int fr = 0; fr < 4; ++fr)
            #pragma unroll
            for (int fc = 0; fc < 4; ++fc)
                acc[fr][fc] = __builtin_amdgcn_mfma_f32_16x16x32_f16(
                    af[fr], wf[fc], acc[fr][fc], 0, 0, 0);
        __syncthreads();
    }

    int rq = l >> 4;   // 0..3
    #pragma unroll
    for (int fc = 0; fc < 4; ++fc) {
        int v = cb * 128 + wc * 64 + fc * 16 + rl;
        float bv = out_b[v];
        #pragma unroll
        for (int fr = 0; fr < 4; ++fr) {
            #pragma unroll
            for (int r = 0; r < 4; ++r) {
                int row = rb * 128 + wr * 64 + fr * 16 + rq * 4 + r;  // tb = t*B + b
                int t = row >> 3, b = row & 7;
                out[((size_t)(b * S + t)) * V + v] = acc[fr][fc][r] + bv;
            }
        }
    }
}

// ---------------------------------------------------------------- fp32 fallback logits
constexpr int GBM = 256, GBN = 64, GBK = 32;
constexpr int LDA = GBM + 4;
constexpr int LDW = GBN + 4;

__global__ __launch_bounds__(256) void logits_kernel(const float* __restrict__ out_w,
                                                     const float* __restrict__ out_b,
                                                     const float* __restrict__ ws,
                                                     float* __restrict__ out) {
    __shared__ float As[GBK][LDA];
    __shared__ float Wsh[GBK][LDW];
    const float* XR = ws + OFF_XR;
    const float* XI = ws + OFF_XI;
    int cb = blockIdx.x % (V / GBN);
    int rb = blockIdx.x / (V / GBN);
    int tid = threadIdx.x;
    int tx = tid & 7;
    int ty = tid >> 3;
    int m_base = ty * 8;
    int n0 = tx * 8;
    float acc[8][8];
    #pragma unroll
    for (int r = 0; r < 8; ++r)
        #pragma unroll
        for (int c = 0; c < 8; ++c) acc[r][c] = 0.f;

    for (int kc = 0; kc < TWO_D; kc += GBK) {
        #pragma unroll
        for (int j = 0; j < 32; ++j) {
            int idx = tid + j * 256;
            int k = idx & 31;
            int m = idx >> 5;
            int kgl = kc + k;
            int row = rb * GBM + m;
            As[k][m] = (kgl < D) ? XR[row * D + kgl] : XI[row * D + (kgl - D)];
        }
        #pragma unroll
        for (int j = 0; j < 8; ++j) {
            int idx = tid + j * 256;
            int k = idx & 31;
            int n = idx >> 5;
            Wsh[k][n] = out_w[(size_t)(cb * GBN + n) * TWO_D + kc + k];
        }
        __syncthreads();
        #pragma unroll 8
        for (int k = 0; k < GBK; ++k) {
            float4 a0 = *(const float4*)&As[k][m_base];
            float4 a1 = *(const float4*)&As[k][m_base + 4];
            float4 w0 = *(const float4*)&Wsh[k][n0];
            float4 w1 = *(const float4*)&Wsh[k][n0 + 4];
            float am[8] = {a0.x, a0.y, a0.z, a0.w, a1.x, a1.y, a1.z, a1.w};
            float wn[8] = {w0.x, w0.y, w0.z, w0.w, w1.x, w1.y, w1.z, w1.w};
            #pragma unroll
            for (int r = 0; r < 8; ++r)
                #pragma unroll
                for (int c = 0; c < 8; ++c)
                    acc[r][c] = fmaf(am[r], wn[c], acc[r][c]);
        }
        __syncthreads();
    }
    int v0 = cb * GBN + n0;
    float4 ob0 = *(const float4*)&out_b[v0];
    float4 ob1 = *(const float4*)&out_b[v0 + 4];
    float obn[8] = {ob0.x, ob0.y, ob0.z, ob0.w, ob1.x, ob1.y, ob1.z, ob1.w};
    #pragma unroll
    for (int r = 0; r < 8; ++r) {
        int row = rb * GBM + m_base + r;
        int t = row >> 3;
        int b = row & 7;
        float o[8];
        #pragma unroll
        for (int c = 0; c < 8; ++c) o[c] = acc[r][c] + obn[c];
        *(float4*)&out[((size_t)(b * S + t)) * V + v0]     = *(float4*)&o[0];
        *(float4*)&out[((size_t)(b * S + t)) * V + v0 + 4] = *(float4*)&o[4];
    }
}

// ---------------------------------------------------------------- launcher
extern "C" void kernel_launch(void* const* d_in, const int* in_sizes, int n_in,
                              void* d_out, int out_size, void* d_ws, size_t ws_size,
                              hipStream_t stream) {
    const int*   ids   = (const int*)d_in[0];
    const float* emb   = (const float*)d_in[1];
    const float* ip_w  = (const float*)d_in[2];
    const float* ip_b  = (const float*)d_in[3];
    const float* Wn    = (const float*)d_in[4];
    const float* Bn    = (const float*)d_in[5];
    const float* opr   = (const float*)d_in[6];
    const float* opi   = (const float*)d_in[7];
    const float* out_w = (const float*)d_in[8];
    const float* out_b = (const float*)d_in[9];
    float* out = (float*)d_out;
    float* ws  = (float*)d_ws;
    const bool use_mfma = (ws_size >= WS_NEED);
    u16* A2 = (u16*)((char*)d_ws + A2_BYTE_OFF);
    u16* W2 = (u16*)((char*)d_ws + W2_BYTE_OFF);

    int prep_blocks = 1024 + (use_mfma ? (V * 128 / 256) : 0);
    hipLaunchKernelGGL(prepconv_kernel, dim3(prep_blocks), dim3(256), 0, stream,
                       Wn, Bn, ip_w, opr, opi, out_w, ws, W2);
    hipLaunchKernelGGL(recur_kernel, dim3(32), dim3(64), 0, stream, ids, emb, ws);
    hipLaunchKernelGGL(layers_kernel, dim3(M / 4), dim3(256), 0, stream,
                       ip_b, ws, A2, use_mfma ? 1 : 0);
    if (use_mfma) {
        hipLaunchKernelGGL(logits_mfma_kernel, dim3((V / 128) * (M / 128)), dim3(256), 0, stream,
                           A2, W2, out_b, out);
    } else {
        hipLaunchKernelGGL(logits_kernel, dim3((V / GBN) * (M / GBM)), dim3(256), 0, stream,
                           out_w, out_b, ws, out);
    }
}

// Round 13
// 481.588 us; speedup vs baseline: 1.0827x; 1.0827x over previous
//
#include <hip/hip_runtime.h>
#include <hip/hip_fp16.h>
#include <math.h>

// SmallRIN forward — 4 dispatches.
//  - prepconv: weight transposes + out_w->fp16 (block-range fused)
//  - recur: scalar-u trig-identity chain, LDS-staged
//  - layers: xc+theta+update for BOTH layers + A->fp16; 512 threads/block,
//    reduction axes split across thread-halves (8 waves/CU, 2x latency hiding)
//  - logits: fp16 MFMA 128x128 tile, rb-fast for W reuse

#define PHIF 1.6180339887498949f

typedef unsigned short u16;
typedef __attribute__((ext_vector_type(8))) _Float16 f16x8;
typedef __attribute__((ext_vector_type(4))) float f32x4;

constexpr int B = 8, S = 128, V = 32000, D = 256, N = 256, L = 2;
constexpr int TWO_D = 512;
constexpr int M = S * B; // 1024 rows, row index tb = t*B + b

// workspace layout (float units)
constexpr size_t OFF_XR   = 0;                                  // [M][D]
constexpr size_t OFF_XI   = OFF_XR   + (size_t)M * D;           // [M][D]
constexpr size_t OFF_XC   = OFF_XI   + (size_t)M * D;           // (unused, kept for layout)
constexpr size_t OFF_CS   = OFF_XC   + (size_t)M * D;           // (unused)
constexpr size_t OFF_SS   = OFF_CS   + (size_t)M * N;           // (unused)
constexpr size_t OFF_RWT  = OFF_SS   + (size_t)M * N;           // [L][D][N] 1/(1+|Wn|) transposed
constexpr size_t OFF_BNT  = OFF_RWT  + (size_t)L * N * D;       // [L][D][N] Bn transposed
constexpr size_t OFF_IPWT = OFF_BNT  + (size_t)L * N * D;       // [L][2D][D] ip_w^T
constexpr size_t OFF_OPRT = OFF_IPWT + (size_t)L * TWO_D * D;   // [L][N][D]  opr^T
constexpr size_t OFF_OPIT = OFF_OPRT + (size_t)L * N * D;       // [L][N][D]  opi^T
constexpr size_t OFF_FLT_END = OFF_OPIT + (size_t)L * N * D;    // 2,097,152 floats = 8 MB

// fp16 buffers (byte offsets into ws)
constexpr size_t A2_BYTE_OFF = OFF_FLT_END * 4;                       // [M][512] f16 = 1 MB
constexpr size_t W2_BYTE_OFF = A2_BYTE_OFF + (size_t)M * 512 * 2;     // [V][512] f16 = 32.8 MB
constexpr size_t WS_NEED     = W2_BYTE_OFF + (size_t)V * 512 * 2;     // ~41.8 MB

__device__ __forceinline__ u16 f2h(float x) {
    return __half_as_ushort(__float2half(x));   // RNE
}

// ---------------------------------------------------------------- prep + conv_w fused
// blocks [0,1024): transposes; blocks [1024,1024+16000): out_w -> fp16
__global__ __launch_bounds__(256) void prepconv_kernel(const float* __restrict__ Wn,
                                                       const float* __restrict__ Bn,
                                                       const float* __restrict__ ip_w,
                                                       const float* __restrict__ opr,
                                                       const float* __restrict__ opi,
                                                       const float* __restrict__ out_w,
                                                       float* __restrict__ ws,
                                                       u16* __restrict__ W2) {
    int blk = blockIdx.x;
    if (blk < 1024) {
        int i = blk * 256 + threadIdx.x;   // 0..262143
        if (i < L * N * D) {
            int l = i >> 16;
            int r = i & 65535;
            int a = r >> 8;          // slow index of the WRITE
            int c = r & 255;         // fast index of the WRITE (coalesced)
            float wv = Wn[(size_t)l * N * D + (size_t)c * D + a];
            ws[OFF_RWT + i] = 1.0f / (1.0f + fabsf(wv));
            ws[OFF_BNT + i] = Bn[(size_t)l * N * D + (size_t)c * D + a];
            ws[OFF_OPRT + i] = opr[(size_t)l * D * N + (size_t)c * N + a];
            ws[OFF_OPIT + i] = opi[(size_t)l * D * N + (size_t)c * N + a];
        }
        // all i < 262144 valid for IPWT
        int l = i >> 17;
        int r = i & 131071;
        int k = r >> 8;
        int d = r & 255;
        ws[OFF_IPWT + i] = ip_w[(size_t)l * D * TWO_D + (size_t)d * TWO_D + k];
    } else {
        int gid = (blk - 1024) * 256 + threadIdx.x;  // V*128 = 4,096,000
        if (gid >= V * 128) return;
        int v  = gid >> 7;
        int kq = (gid & 127) << 2;
        float4 x = *(const float4*)&out_w[(size_t)v * TWO_D + kq];
        ushort4 h = {f2h(x.x), f2h(x.y), f2h(x.z), f2h(x.w)};
        *(ushort4*)&W2[(size_t)v * 512 + kq] = h;
    }
}

// ---------------------------------------------------------------- recurrence
// Identity: h_r' = cos(th_r+th_i), h_i' = sin(th_r+th_i);
//   th_r+th_i = (h_r+h_i)/wl + 2*b + 2*t*phi  -> scalar chain in u = h_r+h_i.
__global__ __launch_bounds__(64) void recur_kernel(const int* __restrict__ ids,
                                                   const float* __restrict__ emb,
                                                   float* __restrict__ ws) {
    __shared__ int   sid[S];
    __shared__ float swv[S][64];
    __shared__ float sbv[S][64];
    int lane = threadIdx.x;          // 0..63
    int blk  = blockIdx.x;           // 0..31
    int b  = blk >> 2;               // 4 blocks per batch row
    int d  = (blk & 3) * 64 + lane;
    sid[lane]      = ids[b * S + lane];
    sid[64 + lane] = ids[b * S + 64 + lane];
    __syncthreads();
    #pragma unroll 16
    for (int t = 0; t < S; ++t) {
        const float* e = emb + (size_t)sid[t] * TWO_D;
        swv[t][lane] = e[d];
        sbv[t][lane] = e[D + d];
    }
    __syncthreads();
    float* XR = ws + OFF_XR;
    float* XI = ws + OFF_XI;
    float u = 0.f;
    #pragma unroll 8
    for (int t = 0; t < S; ++t) {
        float wl = 1.0f + fabsf(swv[t][lane]);
        float c  = 2.0f * sbv[t][lane] + (2.0f * PHIF) * (float)t;
        float psi = __fdividef(u, wl) + c;
        float sn = __sinf(psi);
        float cs = __cosf(psi);
        size_t row = (size_t)(t * B + b) * D + d;
        XR[row] = cs;
        XI[row] = sn;
        u = cs + sn;
    }
}

// ---------------------------------------------------------------- fused resonant layers
// 4 rows/block, 512 threads. Each phase's REDUCTION axis is split across the
// two 256-thread halves (xc: k-half; theta: d-half; update: n-half); partials
// combined via LDS scratch. 8 waves/CU; unroll-8 for load pipelining.
__global__ __launch_bounds__(512) void layers_kernel(const float* __restrict__ ipb,
                                                     float* __restrict__ ws,
                                                     u16* __restrict__ A2,
                                                     int use_a2) {
    __shared__ float xr[4][D];
    __shared__ float xi[4][D];
    __shared__ float xc[4][D];
    __shared__ float cs[4][N];
    __shared__ float ss[4][N];
    __shared__ float p0[4][N];
    __shared__ float p1[4][N];
    int m0 = blockIdx.x * 4;
    int tid = threadIdx.x;        // 0..511
    int half = tid >> 8;          // 0/1
    int id = tid & 255;           // d or n depending on phase

    for (int e = tid; e < 4 * D; e += 512) {
        int r = e >> 8, d = e & 255;
        xr[r][d] = ws[OFF_XR + (size_t)(m0 + r) * D + d];
        xi[r][d] = ws[OFF_XI + (size_t)(m0 + r) * D + d];
    }
    float tp[4];
    #pragma unroll
    for (int r = 0; r < 4; ++r) tp[r] = (float)((m0 + r) >> 3) * PHIF;

    for (int l = 0; l < L; ++l) {
        __syncthreads();
        // ---- xc partials: thread owns d=id; half0 sums xr-part, half1 xi-part
        const float* WT = ws + OFF_IPWT + (size_t)l * TWO_D * D;
        {
            float a[4] = {0.f, 0.f, 0.f, 0.f};
            if (half == 0) {
                #pragma unroll 8
                for (int k = 0; k < D; ++k) {
                    float wv = WT[k * D + id];
                    #pragma unroll
                    for (int r = 0; r < 4; ++r) a[r] = fmaf(xr[r][k], wv, a[r]);
                }
                #pragma unroll
                for (int r = 0; r < 4; ++r) xc[r][id] = a[r];
            } else {
                #pragma unroll 8
                for (int k = 0; k < D; ++k) {
                    float wv = WT[(k + D) * D + id];
                    #pragma unroll
                    for (int r = 0; r < 4; ++r) a[r] = fmaf(xi[r][k], wv, a[r]);
                }
                #pragma unroll
                for (int r = 0; r < 4; ++r) p0[r][id] = a[r];
            }
        }
        __syncthreads();
        for (int e = tid; e < 4 * D; e += 512) {
            int r = e >> 8, d = e & 255;
            xc[r][d] += p0[r][d] + ipb[l * D + d];
        }
        __syncthreads();

        // ---- theta partials: thread owns n=id, d-range [half*128, half*128+128)
        const float* RW = ws + OFF_RWT + (size_t)l * D * N;
        const float* BN = ws + OFF_BNT + (size_t)l * D * N;
        {
            float ac[4] = {0.f, 0.f, 0.f, 0.f};
            float av[4] = {0.f, 0.f, 0.f, 0.f};
            int dbase = half * 128;
            #pragma unroll 8
            for (int dd = 0; dd < 128; ++dd) {
                int d = dbase + dd;
                float rw = RW[d * N + id];
                float bn = BN[d * N + id];
                #pragma unroll
                for (int r = 0; r < 4; ++r) {
                    float th = fmaf(xc[r][d], rw, bn) + tp[r];
                    ac[r] += __cosf(th);
                    av[r] += __sinf(th);
                }
            }
            if (half == 0) {
                #pragma unroll
                for (int r = 0; r < 4; ++r) { cs[r][id] = ac[r]; ss[r][id] = av[r]; }
            } else {
                #pragma unroll
                for (int r = 0; r < 4; ++r) { p0[r][id] = ac[r]; p1[r][id] = av[r]; }
            }
        }
        __syncthreads();
        for (int e = tid; e < 4 * N; e += 512) {
            int r = e >> 8, n = e & 255;
            cs[r][n] += p0[r][n];
            ss[r][n] += p1[r][n];
        }
        __syncthreads();

        // ---- update partials: thread owns d=id, n-range [half*128, half*128+128)
        const float* WR = ws + OFF_OPRT + (size_t)l * N * D;
        const float* WI = ws + OFF_OPIT + (size_t)l * N * D;
        {
            float ur[4] = {0.f, 0.f, 0.f, 0.f};
            float ui[4] = {0.f, 0.f, 0.f, 0.f};
            int nbase = half * 128;
            #pragma unroll 8
            for (int nn = 0; nn < 128; ++nn) {
                int n = nbase + nn;
                float wr = WR[n * D + id];
                float wi = WI[n * D + id];
                #pragma unroll
                for (int r = 0; r < 4; ++r) {
                    ur[r] = fmaf(cs[r][n], wr, ur[r]);
                    ui[r] = fmaf(ss[r][n], wi, ui[r]);
                }
            }
            if (half == 1) {
                #pragma unroll
                for (int r = 0; r < 4; ++r) { p0[r][id] = ur[r]; p1[r][id] = ui[r]; }
            }
            __syncthreads();
            if (half == 0) {
                #pragma unroll
                for (int r = 0; r < 4; ++r) {
                    float vr = ur[r] + p0[r][id];
                    float vi = ui[r] + p1[r][id];
                    float sgr = 1.0f / (1.0f + expf(-vr));
                    float sgi = 1.0f / (1.0f + expf(-vi));
                    xr[r][id] += vr * sgr;
                    xi[r][id] += vi * sgi;
                }
            }
        }
    }
    __syncthreads();
    // ---- write back final state (+fp16 A2 for the MFMA logits)
    for (int e = tid; e < 4 * D; e += 512) {
        int r = e >> 8, d = e & 255;
        float vr = xr[r][d];
        float vi = xi[r][d];
        ws[OFF_XR + (size_t)(m0 + r) * D + d] = vr;
        ws[OFF_XI + (size_t)(m0 + r) * D + d] = vi;
        if (use_a2) {
            A2[(size_t)(m0 + r) * 512 + d]       = f2h(vr);
            A2[(size_t)(m0 + r) * 512 + 256 + d] = f2h(vi);
        }
    }
}

// ---------------------------------------------------------------- logits via fp16 MFMA
// rb is the FAST block index: 8 consecutive blocks share one W 128-row tile.
__global__ __launch_bounds__(256) void logits_mfma_kernel(const u16* __restrict__ A2,
                                                          const u16* __restrict__ W2,
                                                          const float* __restrict__ out_b,
                                                          float* __restrict__ out) {
    __shared__ u16 sA[128 * 32];  // 8 KB, row-major [128][32]
    __shared__ u16 sW[128 * 32];  // 8 KB
    int rb = blockIdx.x & 7;           // 8 row blocks (fast)
    int cb = blockIdx.x >> 3;          // 250 col blocks
    int tid = threadIdx.x;
    int w = tid >> 6, l = tid & 63;
    int wr = w >> 1, wc = w & 1;

    f32x4 acc[4][4];
    #pragma unroll
    for (int i = 0; i < 4; ++i)
        #pragma unroll
        for (int j = 0; j < 4; ++j) acc[i][j] = (f32x4){0.f, 0.f, 0.f, 0.f};

    int srow = l >> 2;          // 0..15
    int sko  = (l & 3) * 8;     // 0,8,16,24 (u16 units -> 16B)
    int kg = (l >> 4) * 8;      // frag k offset
    int rl = l & 15;            // frag row/col

    for (int kk = 0; kk < 512; kk += 32) {
        #pragma unroll
        for (int j = 0; j < 2; ++j) {
            int rloc = (w * 2 + j) * 16 + srow;
            const u16* sa = A2 + (size_t)(rb * 128 + rloc) * 512 + kk + sko;
            const u16* sw = W2 + (size_t)(cb * 128 + rloc) * 512 + kk + sko;
            u16* da = &sA[rloc * 32 + sko];
            u16* dw = &sW[rloc * 32 + sko];
            __builtin_amdgcn_global_load_lds((const __attribute__((address_space(1))) void*)sa,
                                             (__attribute__((address_space(3))) void*)da, 16, 0, 0);
            __builtin_amdgcn_global_load_lds((const __attribute__((address_space(1))) void*)sw,
                                             (__attribute__((address_space(3))) void*)dw, 16, 0, 0);
        }
        __syncthreads();
        f16x8 af[4], wf[4];
        #pragma unroll
        for (int f = 0; f < 4; ++f) {
            af[f] = *(const f16x8*)&sA[(wr * 64 + f * 16 + rl) * 32 + kg];
            wf[f] = *(const f16x8*)&sW[(wc * 64 + f * 16 + rl) * 32 + kg];
        }
        #pragma unroll
        for (int fr = 0; fr < 4; ++fr)
            #pragma unroll
            for (int fc = 0; fc < 4; ++fc)
                acc[fr][fc] = __builtin_amdgcn_mfma_f32_16x16x32_f16(
                    af[fr], wf[fc], acc[fr][fc], 0, 0, 0);
        __syncthreads();
    }

    int rq = l >> 4;   // 0..3
    #pragma unroll
    for (int fc = 0; fc < 4; ++fc) {
        int v = cb * 128 + wc * 64 + fc * 16 + rl;
        float bv = out_b[v];
        #pragma unroll
        for (int fr = 0; fr < 4; ++fr) {
            #pragma unroll
            for (int r = 0; r < 4; ++r) {
                int row = rb * 128 + wr * 64 + fr * 16 + rq * 4 + r;  // tb = t*B + b
                int t = row >> 3, b = row & 7;
                out[((size_t)(b * S + t)) * V + v] = acc[fr][fc][r] + bv;
            }
        }
    }
}

// ---------------------------------------------------------------- fp32 fallback logits
constexpr int GBM = 256, GBN = 64, GBK = 32;
constexpr int LDA = GBM + 4;
constexpr int LDW = GBN + 4;

__global__ __launch_bounds__(256) void logits_kernel(const float* __restrict__ out_w,
                                                     const float* __restrict__ out_b,
                                                     const float* __restrict__ ws,
                                                     float* __restrict__ out) {
    __shared__ float As[GBK][LDA];
    __shared__ float Wsh[GBK][LDW];
    const float* XR = ws + OFF_XR;
    const float* XI = ws + OFF_XI;
    int cb = blockIdx.x % (V / GBN);
    int rb = blockIdx.x / (V / GBN);
    int tid = threadIdx.x;
    int tx = tid & 7;
    int ty = tid >> 3;
    int m_base = ty * 8;
    int n0 = tx * 8;
    float acc[8][8];
    #pragma unroll
    for (int r = 0; r < 8; ++r)
        #pragma unroll
        for (int c = 0; c < 8; ++c) acc[r][c] = 0.f;

    for (int kc = 0; kc < TWO_D; kc += GBK) {
        #pragma unroll
        for (int j = 0; j < 32; ++j) {
            int idx = tid + j * 256;
            int k = idx & 31;
            int m = idx >> 5;
            int kgl = kc + k;
            int row = rb * GBM + m;
            As[k][m] = (kgl < D) ? XR[row * D + kgl] : XI[row * D + (kgl - D)];
        }
        #pragma unroll
        for (int j = 0; j < 8; ++j) {
            int idx = tid + j * 256;
            int k = idx & 31;
            int n = idx >> 5;
            Wsh[k][n] = out_w[(size_t)(cb * GBN + n) * TWO_D + kc + k];
        }
        __syncthreads();
        #pragma unroll 8
        for (int k = 0; k < GBK; ++k) {
            float4 a0 = *(const float4*)&As[k][m_base];
            float4 a1 = *(const float4*)&As[k][m_base + 4];
            float4 w0 = *(const float4*)&Wsh[k][n0];
            float4 w1 = *(const float4*)&Wsh[k][n0 + 4];
            float am[8] = {a0.x, a0.y, a0.z, a0.w, a1.x, a1.y, a1.z, a1.w};
            float wn[8] = {w0.x, w0.y, w0.z, w0.w, w1.x, w1.y, w1.z, w1.w};
            #pragma unroll
            for (int r = 0; r < 8; ++r)
                #pragma unroll
                for (int c = 0; c < 8; ++c)
                    acc[r][c] = fmaf(am[r], wn[c], acc[r][c]);
        }
        __syncthreads();
    }
    int v0 = cb * GBN + n0;
    float4 ob0 = *(const float4*)&out_b[v0];
    float4 ob1 = *(const float4*)&out_b[v0 + 4];
    float obn[8] = {ob0.x, ob0.y, ob0.z, ob0.w, ob1.x, ob1.y, ob1.z, ob1.w};
    #pragma unroll
    for (int r = 0; r < 8; ++r) {
        int row = rb * GBM + m_base + r;
        int t = row >> 3;
        int b = row & 7;
        float o[8];
        #pragma unroll
        for (int c = 0; c < 8; ++c) o[c] = acc[r][c] + obn[c];
        *(float4*)&out[((size_t)(b * S + t)) * V + v0]     = *(float4*)&o[0];
        *(float4*)&out[((size_t)(b * S + t)) * V + v0 + 4] = *(float4*)&o[4];
    }
}

// ---------------------------------------------------------------- launcher
extern "C" void kernel_launch(void* const* d_in, const int* in_sizes, int n_in,
                              void* d_out, int out_size, void* d_ws, size_t ws_size,
                              hipStream_t stream) {
    const int*   ids   = (const int*)d_in[0];
    const float* emb   = (const float*)d_in[1];
    const float* ip_w  = (const float*)d_in[2];
    const float* ip_b  = (const float*)d_in[3];
    const float* Wn    = (const float*)d_in[4];
    const float* Bn    = (const float*)d_in[5];
    const float* opr   = (const float*)d_in[6];
    const float* opi   = (const float*)d_in[7];
    const float* out_w = (const float*)d_in[8];
    const float* out_b = (const float*)d_in[9];
    float* out = (float*)d_out;
    float* ws  = (float*)d_ws;
    const bool use_mfma = (ws_size >= WS_NEED);
    u16* A2 = (u16*)((char*)d_ws + A2_BYTE_OFF);
    u16* W2 = (u16*)((char*)d_ws + W2_BYTE_OFF);

    int prep_blocks = 1024 + (use_mfma ? (V * 128 / 256) : 0);
    hipLaunchKernelGGL(prepconv_kernel, dim3(prep_blocks), dim3(256), 0, stream,
                       Wn, Bn, ip_w, opr, opi, out_w, ws, W2);
    hipLaunchKernelGGL(recur_kernel, dim3(32), dim3(64), 0, stream, ids, emb, ws);
    hipLaunchKernelGGL(layers_kernel, dim3(M / 4), dim3(512), 0, stream,
                       ip_b, ws, A2, use_mfma ? 1 : 0);
    if (use_mfma) {
        hipLaunchKernelGGL(logits_mfma_kernel, dim3((V / 128) * (M / 128)), dim3(256), 0, stream,
                           A2, W2, out_b, out);
    } else {
        hipLaunchKernelGGL(logits_kernel, dim3((V / GBN) * (M / GBM)), dim3(256), 0, stream,
                           out_w, out_b, ws, out);
    }
}